// Round 3
// baseline (213.477 us; speedup 1.0000x reference)
//
#include <hip/hip_runtime.h>
#include <stdint.h>

#define NB 262144
#define D 128
#define K 10

#define BLK_THREADS 256
#define ROWS_PER_BLK 512
#define NBLK1 (NB / ROWS_PER_BLK)   // 512 blocks
#define CHUNK 16                    // dims per LDS chunk
#define NCHUNK (D / CHUNK)          // 8

// ---------------- Kernel 1: q + column partial sums ----------------
__global__ __launch_bounds__(BLK_THREADS) void qkern(
    const float* __restrict__ z, const float* __restrict__ centers,
    float* __restrict__ qout, float* __restrict__ f) {
  __shared__ float buf[2][ROWS_PER_BLK * CHUNK];   // 2 x 32 KB
  __shared__ float c_lds[K * D];                   // 5 KB
  __shared__ float red[4][K];

  const int t = threadIdx.x;
  const int w = t >> 6;
  const int lane = t & 63;
  const int row0 = blockIdx.x * ROWS_PER_BLK;

  // centers -> LDS
  for (int i = t; i < K * D; i += BLK_THREADS) c_lds[i] = centers[i];
  __syncthreads();

  // stage chunk `c` of z-tile into buf[cb]; linear LDS dest, source
  // pre-permuted with the float4-slot XOR swizzle (slot ^= (r>>1)&3)
  auto stage = [&](int cb, int c) {
    const float* zc = z + (size_t)row0 * D + c * CHUNK;
#pragma unroll
    for (int i = 0; i < 8; ++i) {
      int ubase = w * 512 + i * 64;          // float4-unit base (wave-uniform)
      int unit = ubase + lane;
      int r = unit >> 2;
      int d4 = (unit & 3) ^ ((r >> 1) & 3);  // inverse swizzle on source
      const float* src = zc + r * D + d4 * 4;
      float* dst = &buf[cb][ubase * 4];
      __builtin_amdgcn_global_load_lds(
          (const __attribute__((address_space(1))) void*)src,
          (__attribute__((address_space(3))) void*)dst, 16, 0, 0);
    }
  };

  float acc[2][K];
#pragma unroll
  for (int r2 = 0; r2 < 2; ++r2)
#pragma unroll
    for (int j = 0; j < K; ++j) acc[r2][j] = 0.f;

  stage(0, 0);
  for (int c = 0; c < NCHUNK; ++c) {
    const int cur = c & 1;
    if (c + 1 < NCHUNK) {
      stage(cur ^ 1, c + 1);
      asm volatile("s_waitcnt vmcnt(8)" ::: "memory");  // my chunk-c loads done
    } else {
      asm volatile("s_waitcnt vmcnt(0)" ::: "memory");
    }
    __builtin_amdgcn_s_barrier();            // all waves' chunk-c staged

#pragma unroll
    for (int s = 0; s < 4; ++s) {
      float4 zf[2];
#pragma unroll
      for (int r2 = 0; r2 < 2; ++r2) {
        int r = t + r2 * 256;
        int slot = s ^ ((r >> 1) & 3);       // swizzled read
        zf[r2] = *reinterpret_cast<const float4*>(&buf[cur][(r * 4 + slot) * 4]);
      }
#pragma unroll
      for (int j = 0; j < K; ++j) {
        float4 cf = *reinterpret_cast<const float4*>(&c_lds[j * D + c * CHUNK + s * 4]);
#pragma unroll
        for (int r2 = 0; r2 < 2; ++r2) {
          float dx = zf[r2].x - cf.x; acc[r2][j] = fmaf(dx, dx, acc[r2][j]);
          float dy = zf[r2].y - cf.y; acc[r2][j] = fmaf(dy, dy, acc[r2][j]);
          float dz = zf[r2].z - cf.z; acc[r2][j] = fmaf(dz, dz, acc[r2][j]);
          float dw = zf[r2].w - cf.w; acc[r2][j] = fmaf(dw, dw, acc[r2][j]);
        }
      }
    }
    asm volatile("s_waitcnt lgkmcnt(0)" ::: "memory");  // my LDS reads done
    __builtin_amdgcn_s_barrier();            // safe to overwrite other buffer
  }

  // q = (1/(1+d2)) row-normalized; write out; column partials
  float colp[K];
#pragma unroll
  for (int j = 0; j < K; ++j) colp[j] = 0.f;

#pragma unroll
  for (int r2 = 0; r2 < 2; ++r2) {
    float qu[K];
    float srow = 0.f;
#pragma unroll
    for (int j = 0; j < K; ++j) {
      qu[j] = 1.0f / (1.0f + acc[r2][j]);
      srow += qu[j];
    }
    float inv = 1.0f / srow;
    int row = row0 + t + r2 * 256;
    float* qo = qout + (size_t)row * K;
#pragma unroll
    for (int j = 0; j < K; j += 2) {
      float a = qu[j] * inv, b = qu[j + 1] * inv;
      *reinterpret_cast<float2*>(&qo[j]) = make_float2(a, b);
      colp[j] += a;
      colp[j + 1] += b;
    }
  }

  // wave reduce -> block reduce -> atomic
#pragma unroll
  for (int j = 0; j < K; ++j) {
#pragma unroll
    for (int off = 32; off >= 1; off >>= 1)
      colp[j] += __shfl_xor(colp[j], off);
  }
  if (lane == 0) {
#pragma unroll
    for (int j = 0; j < K; ++j) red[w][j] = colp[j];
  }
  __syncthreads();
  if (t < K) {
    float s = red[0][t] + red[1][t] + red[2][t] + red[3][t];
    atomicAdd(&f[t], s);
  }
}

// ---------------- Kernel 2: p from q, f ----------------
__global__ __launch_bounds__(256) void pkern(
    const float* __restrict__ q, const float* __restrict__ f,
    float* __restrict__ p) {
  int row = blockIdx.x * 256 + threadIdx.x;
  const float* qr = q + (size_t)row * K;
  float wv[K];
  float s = 0.f;
#pragma unroll
  for (int j = 0; j < K; j += 2) {
    float2 qq = *reinterpret_cast<const float2*>(&qr[j]);
    wv[j] = qq.x * qq.x / f[j];
    wv[j + 1] = qq.y * qq.y / f[j + 1];
    s += wv[j] + wv[j + 1];
  }
  float inv = 1.0f / s;
  float* pr = p + (size_t)row * K;
#pragma unroll
  for (int j = 0; j < K; j += 2) {
    *reinterpret_cast<float2*>(&pr[j]) = make_float2(wv[j] * inv, wv[j + 1] * inv);
  }
}

extern "C" void kernel_launch(void* const* d_in, const int* in_sizes, int n_in,
                              void* d_out, int out_size, void* d_ws, size_t ws_size,
                              hipStream_t stream) {
  const float* z = (const float*)d_in[0];
  const float* centers = (const float*)d_in[1];
  float* out = (float*)d_out;            // q at [0, NB*K), p at [NB*K, 2*NB*K)
  float* f = (float*)d_ws;               // K column sums

  hipMemsetAsync(d_ws, 0, K * sizeof(float), stream);
  qkern<<<NBLK1, BLK_THREADS, 0, stream>>>(z, centers, out, f);
  pkern<<<NB / 256, 256, 0, stream>>>(out, f, out + (size_t)NB * K);
}